// Round 2
// baseline (682.463 us; speedup 1.0000x reference)
//
#include <hip/hip_runtime.h>
#include <hip/hip_bf16.h>
#include <math.h>

typedef __bf16 bf16;
typedef __bf16 bf16x4 __attribute__((ext_vector_type(4)));
typedef __bf16 bf16x8 __attribute__((ext_vector_type(8)));
typedef float floatx4 __attribute__((ext_vector_type(4)));

#define LOG2E 1.44269504088896340736f

// ---------------- embedding + sinusoidal pos (fp32 emb -> bf16 hids) ----------------
__global__ __launch_bounds__(256) void embed_kernel(const int* __restrict__ data,
                                                    const float* __restrict__ emb,
                                                    bf16* __restrict__ out) {
  int row = blockIdx.x;            // b*1024 + s
  int s = row & 1023;
  int tok = data[row];
  int d = threadIdx.x * 4;
  floatx4 ev = *(const floatx4*)(emb + (size_t)tok * 1024 + d);
  bf16x4 ov;
#pragma unroll
  for (int i = 0; i < 4; i++) {
    int di = d + i;
    float e = -(float)(di & ~1) * (13.287712379549449f / 1024.0f); // log2(10000)/1024
    float freq = exp2f(e);
    float ang = (float)s * freq;
    float pv = (di & 1) ? cosf(ang) : sinf(ang);
    ov[i] = (bf16)(ev[i] * 32.0f + pv);
  }
  *(bf16x4*)(out + (size_t)row * 1024 + d) = ov;
}

// ---------------- transpose + downcast: src fp32 [R][C] -> dst bf16 [C][R] ----------------
__global__ __launch_bounds__(256) void transpose_kernel(const float* __restrict__ src,
                                                        bf16* __restrict__ dst,
                                                        int R, int C) {
  __shared__ __align__(16) bf16 tile[64][72];
  int c0 = blockIdx.x * 64, r0 = blockIdx.y * 64;
  int t = threadIdx.x;
  int r = t >> 2, cg = (t & 3) * 16;
  const float* sp = src + (size_t)(r0 + r) * C + c0 + cg;
  floatx4 f0 = *(const floatx4*)sp;
  floatx4 f1 = *(const floatx4*)(sp + 4);
  floatx4 f2 = *(const floatx4*)(sp + 8);
  floatx4 f3 = *(const floatx4*)(sp + 12);
  bf16x8 v0, v1;
#pragma unroll
  for (int i = 0; i < 4; i++) {
    v0[i] = (bf16)f0[i];
    v0[4 + i] = (bf16)f1[i];
    v1[i] = (bf16)f2[i];
    v1[4 + i] = (bf16)f3[i];
  }
  *(bf16x8*)&tile[r][cg] = v0;
  *(bf16x8*)&tile[r][cg + 8] = v1;
  __syncthreads();
  bf16x8 o0, o1;
#pragma unroll
  for (int i = 0; i < 8; i++) o0[i] = tile[cg + i][r];
#pragma unroll
  for (int i = 0; i < 8; i++) o1[i] = tile[cg + 8 + i][r];
  bf16* dp = dst + (size_t)(c0 + r) * R + r0 + cg;
  *(bf16x8*)dp = o0;
  *(bf16x8*)(dp + 8) = o1;
}

// ---------------- GEMM: C[m][n] = sum_k A[m][k] * Bt[n][k], K=1024, bf16 ----------------
// EPI=0: store bf16 C [M][N].  EPI=1 (KV): n<1024 -> K buffer [4096][1024];
// n>=1024 -> Vt[((b*16+h)*64+d)][s] transposed store.
template <int EPI>
__global__ __launch_bounds__(256) void gemm_kernel(const bf16* __restrict__ A,
                                                   const bf16* __restrict__ Bt,
                                                   bf16* __restrict__ C,
                                                   bf16* __restrict__ Vt, int N) {
  __shared__ __align__(16) bf16 As[128][72];
  __shared__ __align__(16) bf16 Bs[128][72];
  const int K = 1024;
  int m0 = blockIdx.x * 128, n0 = blockIdx.y * 128;
  int t = threadIdx.x;
  int l = t & 63, w = t >> 6;
  int wm = w & 1, wn = w >> 1;
  int lr = l & 15, qd = l >> 4;
  floatx4 acc[4][4] = {};
  int srow = t >> 3, scol = (t & 7) * 8;
  for (int k0 = 0; k0 < K; k0 += 64) {
#pragma unroll
    for (int p = 0; p < 4; p++) {
      int r = srow + p * 32;
      *(bf16x8*)&As[r][scol] = *(const bf16x8*)(A + (size_t)(m0 + r) * K + k0 + scol);
      *(bf16x8*)&Bs[r][scol] = *(const bf16x8*)(Bt + (size_t)(n0 + r) * K + k0 + scol);
    }
    __syncthreads();
#pragma unroll
    for (int c = 0; c < 2; c++) {
      bf16x8 fa[4], fb[4];
#pragma unroll
      for (int i = 0; i < 4; i++) fa[i] = *(bf16x8*)&As[wm * 64 + i * 16 + lr][c * 32 + qd * 8];
#pragma unroll
      for (int j = 0; j < 4; j++) fb[j] = *(bf16x8*)&Bs[wn * 64 + j * 16 + lr][c * 32 + qd * 8];
#pragma unroll
      for (int i = 0; i < 4; i++)
#pragma unroll
        for (int j = 0; j < 4; j++)
          acc[i][j] = __builtin_amdgcn_mfma_f32_16x16x32_bf16(fa[i], fb[j], acc[i][j], 0, 0, 0);
    }
    __syncthreads();
  }
#pragma unroll
  for (int i = 0; i < 4; i++) {
    int mbase = m0 + wm * 64 + i * 16 + qd * 4;
#pragma unroll
    for (int j = 0; j < 4; j++) {
      int n = n0 + wn * 64 + j * 16 + lr;
      if (EPI == 0) {
#pragma unroll
        for (int r = 0; r < 4; r++)
          C[(size_t)(mbase + r) * N + n] = (bf16)acc[i][j][r];
      } else {
        if (n < 1024) {
#pragma unroll
          for (int r = 0; r < 4; r++)
            C[(size_t)(mbase + r) * 1024 + n] = (bf16)acc[i][j][r];
        } else {
          int nn = n - 1024;
          int h = nn >> 6, d = nn & 63;
          int bb = mbase >> 10, s = mbase & 1023;
          bf16x4 v = {(bf16)acc[i][j][0], (bf16)acc[i][j][1],
                      (bf16)acc[i][j][2], (bf16)acc[i][j][3]};
          *(bf16x4*)(Vt + ((size_t)((bb * 16 + h) * 64 + d) << 10) + s) = v;
        }
      }
    }
  }
}

// ---------------- fused attention: 1 wave = 16 queries of one (b,h) ----------------
// Q [4096][1024], Kb [4096][1024], Vt [(b*16+h)*64+d][1024], O [4096][1024]
// memmode: key j<16 -> token 1008+j ; else token j-16 (stage-2 new_mem remap)
__global__ __launch_bounds__(64) void attn_kernel(const bf16* __restrict__ Q,
                                                  const bf16* __restrict__ Kb,
                                                  const bf16* __restrict__ Vt,
                                                  bf16* __restrict__ O,
                                                  int Skv, int memmode) {
  __shared__ __align__(16) bf16 P[2][16][40];
  int bid = blockIdx.x;
  int qb = bid & 63;
  int h = (bid >> 6) & 15;
  int b = bid >> 10;
  int l = threadIdx.x;
  int lr = l & 15, qd = l >> 4;
  int q0 = qb * 16;
  const bf16* Qrow = Q + (size_t)(b * 1024 + q0 + lr) * 1024 + h * 64;
  bf16x8 aq0 = *(const bf16x8*)(Qrow + qd * 8);
  bf16x8 aq1 = *(const bf16x8*)(Qrow + 32 + qd * 8);
  floatx4 Oacc[4] = {};
  float lsum[4] = {0.f, 0.f, 0.f, 0.f};
  const bf16* Kbase = Kb + (size_t)b * 1024 * 1024 + h * 64;
  const bf16* Vbase = Vt + ((size_t)(b * 16 + h) * 64) * 1024;
  int nkt = (Skv + 31) >> 5;
  int vclamp = (Skv - 8) & ~7;
  for (int kt = 0; kt < nkt; kt++) {
    int j0 = kt * 32;
    floatx4 sc[2] = {{0.f, 0.f, 0.f, 0.f}, {0.f, 0.f, 0.f, 0.f}};
#pragma unroll
    for (int s16 = 0; s16 < 2; s16++) {
      int key = j0 + s16 * 16 + lr;
      int kc = min(key, Skv - 1);
      int tokk = memmode ? (kc < 16 ? 1008 + kc : kc - 16) : kc;
      const bf16* kp = Kbase + (size_t)tokk * 1024 + qd * 8;
      bf16x8 kb0 = *(const bf16x8*)kp;
      bf16x8 kb1 = *(const bf16x8*)(kp + 32);
      sc[s16] = __builtin_amdgcn_mfma_f32_16x16x32_bf16(aq0, kb0, sc[s16], 0, 0, 0);
      sc[s16] = __builtin_amdgcn_mfma_f32_16x16x32_bf16(aq1, kb1, sc[s16], 0, 0, 0);
    }
    int pb = kt & 1;
#pragma unroll
    for (int s16 = 0; s16 < 2; s16++) {
      int key = j0 + s16 * 16 + lr;
      float msk = (key < Skv) ? 1.0f : 0.0f;
#pragma unroll
      for (int r = 0; r < 4; r++) {
        float p = exp2f(sc[s16][r] * (0.125f * LOG2E)) * msk;
        lsum[r] += p;
        P[pb][qd * 4 + r][s16 * 16 + lr] = (bf16)p;
      }
    }
    __syncthreads();
    bf16x8 ap = *(const bf16x8*)&P[pb][lr][qd * 8];
    int jb = j0 + qd * 8;
    int jbc = min(jb, vclamp);
    int tokb = memmode ? (jbc < 16 ? 1008 + jbc : jbc - 16) : jbc;
#pragma unroll
    for (int tt = 0; tt < 4; tt++) {
      const bf16* vp = Vbase + (size_t)(tt * 16 + lr) * 1024 + tokb;
      bf16x8 vb = *(const bf16x8*)vp;
      Oacc[tt] = __builtin_amdgcn_mfma_f32_16x16x32_bf16(ap, vb, Oacc[tt], 0, 0, 0);
    }
  }
#pragma unroll
  for (int r = 0; r < 4; r++) {
    float s = lsum[r];
    s += __shfl_xor(s, 1);
    s += __shfl_xor(s, 2);
    s += __shfl_xor(s, 4);
    s += __shfl_xor(s, 8);
    lsum[r] = 1.0f / s;
  }
#pragma unroll
  for (int tt = 0; tt < 4; tt++)
#pragma unroll
    for (int r = 0; r < 4; r++) {
      size_t orow = (size_t)(b * 1024 + q0 + qd * 4 + r) * 1024 + h * 64 + tt * 16 + lr;
      O[orow] = (bf16)(Oacc[tt][r] * lsum[r]);
    }
}

// ---------------- layernorm: out = LN(x + res) * g + b  (bf16 in, OutT out) ----------------
template <typename OutT>
__global__ __launch_bounds__(256) void ln_kernel(const bf16* __restrict__ x,
                                                 const bf16* __restrict__ res,
                                                 const float* __restrict__ g,
                                                 const float* __restrict__ bta,
                                                 OutT* __restrict__ out) {
  __shared__ float red1[4], red2[4];
  int row = blockIdx.x, t = threadIdx.x;
  size_t base = (size_t)row * 1024 + t * 4;
  bf16x4 xv = *(const bf16x4*)(x + base);
  bf16x4 rv = *(const bf16x4*)(res + base);
  float v[4];
  float s = 0.f;
#pragma unroll
  for (int i = 0; i < 4; i++) {
    v[i] = (float)xv[i] + (float)rv[i];
    s += v[i];
  }
#pragma unroll
  for (int m = 32; m; m >>= 1) s += __shfl_xor(s, m);
  if ((t & 63) == 0) red1[t >> 6] = s;
  __syncthreads();
  float mu = (red1[0] + red1[1] + red1[2] + red1[3]) * (1.0f / 1024.0f);
  float sq = 0.f;
#pragma unroll
  for (int i = 0; i < 4; i++) {
    float dd = v[i] - mu;
    sq += dd * dd;
  }
#pragma unroll
  for (int m = 32; m; m >>= 1) sq += __shfl_xor(sq, m);
  if ((t & 63) == 0) red2[t >> 6] = sq;
  __syncthreads();
  float var = (red2[0] + red2[1] + red2[2] + red2[3]) * (1.0f / 1024.0f);
  float rs = rsqrtf(var + 1e-5f);
  floatx4 gv = *(const floatx4*)(g + t * 4);
  floatx4 bv = *(const floatx4*)(bta + t * 4);
  if constexpr (sizeof(OutT) == 2) {
    bf16x4 ov;
#pragma unroll
    for (int i = 0; i < 4; i++)
      ov[i] = (bf16)((v[i] - mu) * rs * gv[i] + bv[i]);
    *(bf16x4*)(out + base) = ov;
  } else {
    floatx4 ov;
#pragma unroll
    for (int i = 0; i < 4; i++)
      ov[i] = (v[i] - mu) * rs * gv[i] + bv[i];
    *(floatx4*)(out + base) = ov;
  }
}

// ---------------- new_mem = hids[:, 1008:1024, :] (bf16 -> fp32 out) ----------------
__global__ __launch_bounds__(256) void copymem_kernel(const bf16* __restrict__ hids,
                                                      float* __restrict__ out) {
  int idx = blockIdx.x * 256 + threadIdx.x;  // 65536
  int bb = idx >> 14;
  int r = (idx >> 10) & 15;
  int d = idx & 1023;
  out[idx] = (float)hids[((size_t)(bb * 1024 + 1008 + r) << 10) + d];
}

extern "C" void kernel_launch(void* const* d_in, const int* in_sizes, int n_in,
                              void* d_out, int out_size, void* d_ws, size_t ws_size,
                              hipStream_t stream) {
  const int* data = (const int*)d_in[0];
  const float* emb = (const float*)d_in[2];
  const float* a_qw = (const float*)d_in[3];
  const float* a_kvw = (const float*)d_in[4];
  const float* a_ow = (const float*)d_in[5];
  const float* a_g = (const float*)d_in[6];
  const float* a_b = (const float*)d_in[7];
  const float* o_qw = (const float*)d_in[16];
  const float* o_kvw = (const float*)d_in[17];
  const float* o_ow = (const float*)d_in[18];
  const float* o_g = (const float*)d_in[19];
  const float* o_b = (const float*)d_in[20];
  const float* ff2_w = (const float*)d_in[21];
  const float* ln1_g = (const float*)d_in[22];
  const float* ln1_b = (const float*)d_in[23];
  const float* ln2_g = (const float*)d_in[24];
  const float* ln2_b = (const float*)d_in[25];
  float* out = (float*)d_out;

  char* ws = (char*)d_ws;
  size_t off = 0;
  auto alloc = [&](size_t elems) {
    bf16* p = (bf16*)(ws + off);
    off += elems * 2;
    return p;
  };
  bf16* Wt_aqw = alloc(1024 * 1024);
  bf16* Wt_akvw = alloc(2048 * 1024);
  bf16* Wt_aow = alloc(1024 * 1024);
  bf16* Wt_oqw = alloc(1024 * 1024);
  bf16* Wt_okvw = alloc(2048 * 1024);
  bf16* Wt_oow = alloc(1024 * 1024);
  bf16* Wt_ff2 = alloc(1024 * 1024);
  bf16* hids0 = alloc(4096 * 1024);  // reused for out_attn at the end
  bf16* hids = alloc(4096 * 1024);
  bf16* Qb = alloc(4096 * 1024);     // reused as proj buffer
  bf16* Kb = alloc(4096 * 1024);
  bf16* Vtb = alloc(4096 * 1024);
  bf16* vecb = alloc(4096 * 1024);   // reused as attn_out
  bf16* projb = Qb;
  bf16* attn_out = vecb;

  dim3 tb(256);
  // weight transposes: src fp32 [K][N] -> bf16 [N][K]
  transpose_kernel<<<dim3(16, 16), tb, 0, stream>>>(a_qw, Wt_aqw, 1024, 1024);
  transpose_kernel<<<dim3(32, 16), tb, 0, stream>>>(a_kvw, Wt_akvw, 1024, 2048);
  transpose_kernel<<<dim3(16, 16), tb, 0, stream>>>(a_ow, Wt_aow, 1024, 1024);
  transpose_kernel<<<dim3(16, 16), tb, 0, stream>>>(o_qw, Wt_oqw, 1024, 1024);
  transpose_kernel<<<dim3(32, 16), tb, 0, stream>>>(o_kvw, Wt_okvw, 1024, 2048);
  transpose_kernel<<<dim3(16, 16), tb, 0, stream>>>(o_ow, Wt_oow, 1024, 1024);
  transpose_kernel<<<dim3(16, 16), tb, 0, stream>>>(ff2_w, Wt_ff2, 1024, 1024);

  embed_kernel<<<4096, tb, 0, stream>>>(data, emb, hids0);

  // stage 1 self-attention
  gemm_kernel<0><<<dim3(32, 8), tb, 0, stream>>>(hids0, Wt_aqw, Qb, nullptr, 1024);
  gemm_kernel<1><<<dim3(32, 16), tb, 0, stream>>>(hids0, Wt_akvw, Kb, Vtb, 2048);
  attn_kernel<<<4096, 64, 0, stream>>>(Qb, Kb, Vtb, vecb, 1024, 0);
  gemm_kernel<0><<<dim3(32, 8), tb, 0, stream>>>(vecb, Wt_aow, projb, nullptr, 1024);
  ln_kernel<bf16><<<4096, tb, 0, stream>>>(projb, hids0, a_g, a_b, hids);

  // stage 2 output attention over [new_mem; hids] (new_mem = hids rows 1008..1023)
  gemm_kernel<0><<<dim3(32, 8), tb, 0, stream>>>(hids, Wt_oqw, Qb, nullptr, 1024);
  gemm_kernel<1><<<dim3(32, 16), tb, 0, stream>>>(hids, Wt_okvw, Kb, Vtb, 2048);
  attn_kernel<<<4096, 64, 0, stream>>>(Qb, Kb, Vtb, vecb, 1040, 1);
  gemm_kernel<0><<<dim3(32, 8), tb, 0, stream>>>(vecb, Wt_oow, projb, nullptr, 1024);
  ln_kernel<bf16><<<4096, tb, 0, stream>>>(projb, hids, o_g, o_b, attn_out);
  ln_kernel<bf16><<<4096, tb, 0, stream>>>(attn_out, hids, ln1_g, ln1_b, hids0);

  // final ff + LN -> d_out (fp32)
  gemm_kernel<0><<<dim3(32, 8), tb, 0, stream>>>(hids0, Wt_ff2, projb, nullptr, 1024);
  ln_kernel<float><<<4096, tb, 0, stream>>>(projb, hids0, ln2_g, ln2_b, out);

  // new_mem output (fp32)
  copymem_kernel<<<256, tb, 0, stream>>>(hids, out + 4194304);
}

// Round 3
// 488.116 us; speedup vs baseline: 1.3982x; 1.3982x over previous
//
#include <hip/hip_runtime.h>
#include <hip/hip_bf16.h>
#include <math.h>

typedef __bf16 bf16;
typedef __bf16 bf16x4 __attribute__((ext_vector_type(4)));
typedef __bf16 bf16x8 __attribute__((ext_vector_type(8)));
typedef float floatx4 __attribute__((ext_vector_type(4)));

#define LOG2E 1.44269504088896340736f
#define AS1 __attribute__((address_space(1)))
#define AS3 __attribute__((address_space(3)))

// async 16B global->LDS. LDS dest must be wave-uniform base; lane i lands at +i*16B.
__device__ __forceinline__ void async_g2l16(const bf16* g, bf16* l) {
  __builtin_amdgcn_global_load_lds((AS1 void*)(void*)g, (AS3 void*)(void*)l, 16, 0, 0);
}

// ---------------- embedding + sinusoidal pos (fp32 emb -> bf16 hids) ----------------
__global__ __launch_bounds__(256) void embed_kernel(const int* __restrict__ data,
                                                    const float* __restrict__ emb,
                                                    bf16* __restrict__ out) {
  int row = blockIdx.x;            // b*1024 + s
  int s = row & 1023;
  int tok = data[row];
  int d = threadIdx.x * 4;
  floatx4 ev = *(const floatx4*)(emb + (size_t)tok * 1024 + d);
  bf16x4 ov;
#pragma unroll
  for (int i = 0; i < 4; i++) {
    int di = d + i;
    float e = -(float)(di & ~1) * (13.287712379549449f / 1024.0f); // log2(10000)/1024
    float freq = exp2f(e);
    float ang = (float)s * freq;
    float pv = (di & 1) ? cosf(ang) : sinf(ang);
    ov[i] = (bf16)(ev[i] * 32.0f + pv);
  }
  *(bf16x4*)(out + (size_t)row * 1024 + d) = ov;
}

// ---------------- transpose + downcast: src fp32 [R][C] -> dst bf16 [C][R] ----------------
__global__ __launch_bounds__(256) void transpose_kernel(const float* __restrict__ src,
                                                        bf16* __restrict__ dst,
                                                        int R, int C) {
  __shared__ __align__(16) bf16 tile[64][72];
  int c0 = blockIdx.x * 64, r0 = blockIdx.y * 64;
  int t = threadIdx.x;
  int r = t >> 2, cg = (t & 3) * 16;
  const float* sp = src + (size_t)(r0 + r) * C + c0 + cg;
  floatx4 f0 = *(const floatx4*)sp;
  floatx4 f1 = *(const floatx4*)(sp + 4);
  floatx4 f2 = *(const floatx4*)(sp + 8);
  floatx4 f3 = *(const floatx4*)(sp + 12);
  bf16x8 v0, v1;
#pragma unroll
  for (int i = 0; i < 4; i++) {
    v0[i] = (bf16)f0[i];
    v0[4 + i] = (bf16)f1[i];
    v1[i] = (bf16)f2[i];
    v1[4 + i] = (bf16)f3[i];
  }
  *(bf16x8*)&tile[r][cg] = v0;
  *(bf16x8*)&tile[r][cg + 8] = v1;
  __syncthreads();
  bf16x8 o0, o1;
#pragma unroll
  for (int i = 0; i < 8; i++) o0[i] = tile[cg + i][r];
#pragma unroll
  for (int i = 0; i < 8; i++) o1[i] = tile[cg + 8 + i][r];
  bf16* dp = dst + (size_t)(c0 + r) * R + r0 + cg;
  *(bf16x8*)dp = o0;
  *(bf16x8*)(dp + 8) = o1;
}

// ---------------- GEMM: C[m][n] = sum_k A[m][k]*Bt[n][k], K=1024, bf16, m97-style ----------
// LDS tiles [rows][64] unpadded; 16B block b of row r stored at column-block b^(r&7)
// (XOR swizzle -> 2-way-free b128 fragment reads; required because global_load_lds
//  destination is lane-ordered and cannot express padding).
// EPI=0: C0[m][n], stride N. EPI=1 (fused QKV, N=3072): n<1024 -> C0 (Q), n<2048 -> C1 (K),
// else -> Vt[((b*16+h)*64+d)][s] transposed store.
template <int EPI, int MT>
__global__ __launch_bounds__(256) void gemm_kernel(const bf16* __restrict__ A,
                                                   const bf16* __restrict__ Bt,
                                                   bf16* __restrict__ C0,
                                                   bf16* __restrict__ C1,
                                                   bf16* __restrict__ Vt, int N) {
  constexpr int NJ = (MT == 128) ? 4 : 2;
  constexpr int PA = MT / 32;   // A-tile async issues per thread
  __shared__ __align__(16) bf16 As[MT * 64];
  __shared__ __align__(16) bf16 Bs[128 * 64];
  const int K = 1024;
  int m0 = blockIdx.x * MT, n0 = blockIdx.y * 128;
  int t = threadIdx.x;
  int l = t & 63, w = t >> 6;
  int lr = l & 15, qd = l >> 4;
  int xorb = lr & 7;
  int wrow = __builtin_amdgcn_readfirstlane(t & 192);  // w*64, wave-uniform
  int wm = (MT == 128) ? (w & 1) : 0;
  int wn = (MT == 128) ? (w >> 1) : w;
  int mwbase = wm * 64;
  int nwbase = (MT == 128) ? (wn * 64) : (wn * 32);
  floatx4 acc[4][NJ] = {};
  for (int k0 = 0; k0 < K; k0 += 64) {
#pragma unroll
    for (int p = 0; p < PA; p++) {
      int jl = p * 256 + t;
      int r = jl >> 3;
      int bi = (jl & 7) ^ (r & 7);
      async_g2l16(A + (size_t)(m0 + r) * K + k0 + bi * 8, &As[(p * 256 + wrow) * 8]);
    }
#pragma unroll
    for (int p = 0; p < 4; p++) {
      int jl = p * 256 + t;
      int r = jl >> 3;
      int bi = (jl & 7) ^ (r & 7);
      async_g2l16(Bt + (size_t)(n0 + r) * K + k0 + bi * 8, &Bs[(p * 256 + wrow) * 8]);
    }
    __syncthreads();
#pragma unroll
    for (int c = 0; c < 2; c++) {
      bf16x8 fa[4], fb[NJ];
#pragma unroll
      for (int i = 0; i < 4; i++)
        fa[i] = *(const bf16x8*)&As[(mwbase + i * 16 + lr) * 64 + ((c * 4 + qd) ^ xorb) * 8];
#pragma unroll
      for (int j = 0; j < NJ; j++)
        fb[j] = *(const bf16x8*)&Bs[(nwbase + j * 16 + lr) * 64 + ((c * 4 + qd) ^ xorb) * 8];
#pragma unroll
      for (int i = 0; i < 4; i++)
#pragma unroll
        for (int j = 0; j < NJ; j++)
          acc[i][j] = __builtin_amdgcn_mfma_f32_16x16x32_bf16(fa[i], fb[j], acc[i][j], 0, 0, 0);
    }
    __syncthreads();
  }
#pragma unroll
  for (int i = 0; i < 4; i++) {
    int mbase = m0 + mwbase + i * 16 + qd * 4;
#pragma unroll
    for (int j = 0; j < NJ; j++) {
      int n = n0 + nwbase + j * 16 + lr;
      if (EPI == 0) {
#pragma unroll
        for (int r = 0; r < 4; r++)
          C0[(size_t)(mbase + r) * N + n] = (bf16)acc[i][j][r];
      } else {
        if (n < 1024) {
#pragma unroll
          for (int r = 0; r < 4; r++)
            C0[(size_t)(mbase + r) * 1024 + n] = (bf16)acc[i][j][r];
        } else if (n < 2048) {
#pragma unroll
          for (int r = 0; r < 4; r++)
            C1[(size_t)(mbase + r) * 1024 + (n - 1024)] = (bf16)acc[i][j][r];
        } else {
          int nn = n - 2048;
          int h = nn >> 6, d = nn & 63;
          int bb = mbase >> 10, s = mbase & 1023;
          bf16x4 v = {(bf16)acc[i][j][0], (bf16)acc[i][j][1],
                      (bf16)acc[i][j][2], (bf16)acc[i][j][3]};
          *(bf16x4*)(Vt + ((size_t)((bb * 16 + h) * 64 + d) << 10) + s) = v;
        }
      }
    }
  }
}

// ---------------- fused flash attention: 256 thr / 4 waves, Br=64 q, Bc=64 keys ----------
// Q,Kb [4096][1024]; Vt [(b*16+h)*64+d][1024]; O [4096][1024]
// memmode: key j<16 -> token 1008+j else j-16 (stage-2 new_mem remap).
// K/V tiles staged async into double-buffered swizzled LDS; one barrier per tile,
// next tile's loads issued before compute so the vmcnt drain overlaps MFMA work.
__global__ __launch_bounds__(256) void attn_kernel(const bf16* __restrict__ Q,
                                                   const bf16* __restrict__ Kb,
                                                   const bf16* __restrict__ Vt,
                                                   bf16* __restrict__ O,
                                                   int Skv, int memmode) {
  __shared__ __align__(16) bf16 Kt[2][64 * 64];   // [buf][key][dim], swizzled blocks
  __shared__ __align__(16) bf16 Vs[2][64 * 64];   // [buf][dim][key], swizzled blocks
  __shared__ __align__(16) bf16 P[4][16][72];     // per-wave P tile, padded (+conflict-free)
  int bid = blockIdx.x;                           // 16 qb x 16 h x 4 b = 1024
  int qb = bid & 15, h = (bid >> 4) & 15, b = bid >> 8;
  int t = threadIdx.x, w = t >> 6, l = t & 63;
  int lr = l & 15, qd = l >> 4;
  int xorb = lr & 7;
  int wrow = __builtin_amdgcn_readfirstlane(t & 192);
  int q0 = qb * 64 + w * 16;
  const bf16* Qrow = Q + (size_t)(b * 1024 + q0 + lr) * 1024 + h * 64;
  bf16x8 aq0 = *(const bf16x8*)(Qrow + qd * 8);
  bf16x8 aq1 = *(const bf16x8*)(Qrow + 32 + qd * 8);
  floatx4 Oacc[4] = {};
  float lsum[4] = {0.f, 0.f, 0.f, 0.f};
  const bf16* Kbase = Kb + (size_t)b * 1024 * 1024 + h * 64;
  const bf16* Vbase = Vt + (size_t)(b * 16 + h) * 64 * 1024;
  int nkt = (Skv + 63) >> 6;

  auto stage = [&](int kt, int bufi) {
    int j0 = kt * 64;
#pragma unroll
    for (int p = 0; p < 2; p++) {
      int jl = p * 256 + t;
      int kr = jl >> 3;                       // key row in tile
      int bi = (jl & 7) ^ (kr & 7);           // swizzled dim-block
      int key = j0 + kr;
      int kc = min(key, Skv - 1);
      int tok = memmode ? (kc < 16 ? 1008 + kc : kc - 16) : kc;
      async_g2l16(Kbase + (size_t)tok * 1024 + bi * 8, &Kt[bufi][(p * 256 + wrow) * 8]);
    }
#pragma unroll
    for (int p = 0; p < 2; p++) {
      int jl = p * 256 + t;
      int dr = jl >> 3;                       // dim row in tile
      int bi = (jl & 7) ^ (dr & 7);           // swizzled key-block
      int jb = j0 + bi * 8;
      int jbc = min(jb, Skv - 8);             // Skv is a multiple of 8
      int tok = memmode ? (jbc < 16 ? 1008 + jbc : jbc - 16) : jbc;
      async_g2l16(Vbase + (size_t)dr * 1024 + tok, &Vs[bufi][(p * 256 + wrow) * 8]);
    }
  };

  stage(0, 0);
  for (int kt = 0; kt < nkt; kt++) {
    int buf = kt & 1;
    __syncthreads();                          // drains tile kt's async loads
    if (kt + 1 < nkt) stage(kt + 1, buf ^ 1); // flies during compute below
    int j0 = kt * 64;
    floatx4 sc[4] = {};
#pragma unroll
    for (int g = 0; g < 4; g++) {
      const bf16* kp = &Kt[buf][(g * 16 + lr) * 64];
      bf16x8 kb0 = *(const bf16x8*)(kp + ((qd ^ xorb) * 8));
      bf16x8 kb1 = *(const bf16x8*)(kp + (((4 + qd) ^ xorb) * 8));
      sc[g] = __builtin_amdgcn_mfma_f32_16x16x32_bf16(aq0, kb0, sc[g], 0, 0, 0);
      sc[g] = __builtin_amdgcn_mfma_f32_16x16x32_bf16(aq1, kb1, sc[g], 0, 0, 0);
    }
#pragma unroll
    for (int g = 0; g < 4; g++) {
      int key = j0 + g * 16 + lr;
      float msk = (key < Skv) ? 1.0f : 0.0f;
#pragma unroll
      for (int r = 0; r < 4; r++) {
        float p = exp2f(sc[g][r] * (0.125f * LOG2E)) * msk;
        lsum[r] += p;
        P[w][qd * 4 + r][g * 16 + lr] = (bf16)p;
      }
    }
#pragma unroll
    for (int c = 0; c < 2; c++) {
      bf16x8 ap = *(const bf16x8*)&P[w][lr][c * 32 + qd * 8];
#pragma unroll
      for (int tt = 0; tt < 4; tt++) {
        const bf16* vp = &Vs[buf][(tt * 16 + lr) * 64];
        bf16x8 vb = *(const bf16x8*)(vp + (((c * 4 + qd) ^ xorb) * 8));
        Oacc[tt] = __builtin_amdgcn_mfma_f32_16x16x32_bf16(ap, vb, Oacc[tt], 0, 0, 0);
      }
    }
  }
#pragma unroll
  for (int r = 0; r < 4; r++) {
    float s = lsum[r];
    s += __shfl_xor(s, 1);
    s += __shfl_xor(s, 2);
    s += __shfl_xor(s, 4);
    s += __shfl_xor(s, 8);
    lsum[r] = 1.0f / s;
  }
#pragma unroll
  for (int tt = 0; tt < 4; tt++)
#pragma unroll
    for (int r = 0; r < 4; r++) {
      size_t orow = (size_t)(b * 1024 + q0 + qd * 4 + r) * 1024 + h * 64 + tt * 16 + lr;
      O[orow] = (bf16)(Oacc[tt][r] * lsum[r]);
    }
}

// ---------------- layernorm: out = LN(x + res) * g + b  (bf16 in, OutT out) ----------------
template <typename OutT>
__global__ __launch_bounds__(256) void ln_kernel(const bf16* __restrict__ x,
                                                 const bf16* __restrict__ res,
                                                 const float* __restrict__ g,
                                                 const float* __restrict__ bta,
                                                 OutT* __restrict__ out) {
  __shared__ float red1[4], red2[4];
  int row = blockIdx.x, t = threadIdx.x;
  size_t base = (size_t)row * 1024 + t * 4;
  bf16x4 xv = *(const bf16x4*)(x + base);
  bf16x4 rv = *(const bf16x4*)(res + base);
  float v[4];
  float s = 0.f;
#pragma unroll
  for (int i = 0; i < 4; i++) {
    v[i] = (float)xv[i] + (float)rv[i];
    s += v[i];
  }
#pragma unroll
  for (int m = 32; m; m >>= 1) s += __shfl_xor(s, m);
  if ((t & 63) == 0) red1[t >> 6] = s;
  __syncthreads();
  float mu = (red1[0] + red1[1] + red1[2] + red1[3]) * (1.0f / 1024.0f);
  float sq = 0.f;
#pragma unroll
  for (int i = 0; i < 4; i++) {
    float dd = v[i] - mu;
    sq += dd * dd;
  }
#pragma unroll
  for (int m = 32; m; m >>= 1) sq += __shfl_xor(sq, m);
  if ((t & 63) == 0) red2[t >> 6] = sq;
  __syncthreads();
  float var = (red2[0] + red2[1] + red2[2] + red2[3]) * (1.0f / 1024.0f);
  float rs = rsqrtf(var + 1e-5f);
  floatx4 gv = *(const floatx4*)(g + t * 4);
  floatx4 bv = *(const floatx4*)(bta + t * 4);
  if constexpr (sizeof(OutT) == 2) {
    bf16x4 ov;
#pragma unroll
    for (int i = 0; i < 4; i++)
      ov[i] = (bf16)((v[i] - mu) * rs * gv[i] + bv[i]);
    *(bf16x4*)(out + base) = ov;
  } else {
    floatx4 ov;
#pragma unroll
    for (int i = 0; i < 4; i++)
      ov[i] = (v[i] - mu) * rs * gv[i] + bv[i];
    *(floatx4*)(out + base) = ov;
  }
}

// ---------------- new_mem = hids[:, 1008:1024, :] (bf16 -> fp32 out) ----------------
__global__ __launch_bounds__(256) void copymem_kernel(const bf16* __restrict__ hids,
                                                      float* __restrict__ out) {
  int idx = blockIdx.x * 256 + threadIdx.x;  // 65536
  int bb = idx >> 14;
  int r = (idx >> 10) & 15;
  int d = idx & 1023;
  out[idx] = (float)hids[((size_t)(bb * 1024 + 1008 + r) << 10) + d];
}

extern "C" void kernel_launch(void* const* d_in, const int* in_sizes, int n_in,
                              void* d_out, int out_size, void* d_ws, size_t ws_size,
                              hipStream_t stream) {
  const int* data = (const int*)d_in[0];
  const float* emb = (const float*)d_in[2];
  const float* a_qw = (const float*)d_in[3];
  const float* a_kvw = (const float*)d_in[4];
  const float* a_ow = (const float*)d_in[5];
  const float* a_g = (const float*)d_in[6];
  const float* a_b = (const float*)d_in[7];
  const float* o_qw = (const float*)d_in[16];
  const float* o_kvw = (const float*)d_in[17];
  const float* o_ow = (const float*)d_in[18];
  const float* o_g = (const float*)d_in[19];
  const float* o_b = (const float*)d_in[20];
  const float* ff2_w = (const float*)d_in[21];
  const float* ln1_g = (const float*)d_in[22];
  const float* ln1_b = (const float*)d_in[23];
  const float* ln2_g = (const float*)d_in[24];
  const float* ln2_b = (const float*)d_in[25];
  float* out = (float*)d_out;

  char* ws = (char*)d_ws;
  size_t off = 0;
  auto alloc = [&](size_t elems) {
    bf16* p = (bf16*)(ws + off);
    off += elems * 2;
    return p;
  };
  bf16* Wt_s1 = alloc(3072 * 1024);   // rows 0..1023 = a_qw^T, 1024..3071 = a_kvw^T
  bf16* Wt_s2 = alloc(3072 * 1024);   // rows 0..1023 = o_qw^T, 1024..3071 = o_kvw^T
  bf16* Wt_aow = alloc(1024 * 1024);
  bf16* Wt_oow = alloc(1024 * 1024);
  bf16* Wt_ff2 = alloc(1024 * 1024);
  bf16* hids0 = alloc(4096 * 1024);   // reused for out_attn at the end
  bf16* hids = alloc(4096 * 1024);
  bf16* Qb = alloc(4096 * 1024);      // reused as proj buffer
  bf16* Kb = alloc(4096 * 1024);
  bf16* Vtb = alloc(4096 * 1024);
  bf16* vecb = alloc(4096 * 1024);    // reused as attn_out
  bf16* projb = Qb;
  bf16* attn_out = vecb;

  dim3 tb(256);
  transpose_kernel<<<dim3(16, 16), tb, 0, stream>>>(a_qw, Wt_s1, 1024, 1024);
  transpose_kernel<<<dim3(32, 16), tb, 0, stream>>>(a_kvw, Wt_s1 + 1024 * 1024, 1024, 2048);
  transpose_kernel<<<dim3(16, 16), tb, 0, stream>>>(o_qw, Wt_s2, 1024, 1024);
  transpose_kernel<<<dim3(32, 16), tb, 0, stream>>>(o_kvw, Wt_s2 + 1024 * 1024, 1024, 2048);
  transpose_kernel<<<dim3(16, 16), tb, 0, stream>>>(a_ow, Wt_aow, 1024, 1024);
  transpose_kernel<<<dim3(16, 16), tb, 0, stream>>>(o_ow, Wt_oow, 1024, 1024);
  transpose_kernel<<<dim3(16, 16), tb, 0, stream>>>(ff2_w, Wt_ff2, 1024, 1024);

  embed_kernel<<<4096, tb, 0, stream>>>(data, emb, hids0);

  // stage 1: fused QKV projection + attention + O-proj + LN
  gemm_kernel<1, 128><<<dim3(32, 24), tb, 0, stream>>>(hids0, Wt_s1, Qb, Kb, Vtb, 3072);
  attn_kernel<<<1024, tb, 0, stream>>>(Qb, Kb, Vtb, vecb, 1024, 0);
  gemm_kernel<0, 64><<<dim3(64, 8), tb, 0, stream>>>(vecb, Wt_aow, projb, nullptr, nullptr, 1024);
  ln_kernel<bf16><<<4096, tb, 0, stream>>>(projb, hids0, a_g, a_b, hids);

  // stage 2: attention over [new_mem; hids] (new_mem = hids rows 1008..1023)
  gemm_kernel<1, 128><<<dim3(32, 24), tb, 0, stream>>>(hids, Wt_s2, Qb, Kb, Vtb, 3072);
  attn_kernel<<<1024, tb, 0, stream>>>(Qb, Kb, Vtb, vecb, 1040, 1);
  gemm_kernel<0, 64><<<dim3(64, 8), tb, 0, stream>>>(vecb, Wt_oow, projb, nullptr, nullptr, 1024);
  ln_kernel<bf16><<<4096, tb, 0, stream>>>(projb, hids, o_g, o_b, attn_out);
  ln_kernel<bf16><<<4096, tb, 0, stream>>>(attn_out, hids, ln1_g, ln1_b, hids0);

  // final ff + LN -> d_out (fp32)
  gemm_kernel<0, 64><<<dim3(64, 8), tb, 0, stream>>>(hids0, Wt_ff2, projb, nullptr, nullptr, 1024);
  ln_kernel<float><<<4096, tb, 0, stream>>>(projb, hids0, ln2_g, ln2_b, out);

  // new_mem output (fp32)
  copymem_kernel<<<256, tb, 0, stream>>>(hids, out + 4194304);
}

// Round 4
// 455.163 us; speedup vs baseline: 1.4994x; 1.0724x over previous
//
#include <hip/hip_runtime.h>
#include <hip/hip_bf16.h>
#include <math.h>

typedef __bf16 bf16;
typedef __bf16 bf16x4 __attribute__((ext_vector_type(4)));
typedef __bf16 bf16x8 __attribute__((ext_vector_type(8)));
typedef float floatx4 __attribute__((ext_vector_type(4)));

#define LOG2E 1.44269504088896340736f
#define AS1 __attribute__((address_space(1)))
#define AS3 __attribute__((address_space(3)))

// async 16B global->LDS. LDS dest must be wave-uniform base; lane i lands at +i*16B.
__device__ __forceinline__ void async_g2l16(const bf16* g, bf16* l) {
  __builtin_amdgcn_global_load_lds((AS1 void*)(void*)g, (AS3 void*)(void*)l, 16, 0, 0);
}

// ---------------- embedding + sinusoidal pos (fp32 emb -> bf16 hids) ----------------
__global__ __launch_bounds__(256) void embed_kernel(const int* __restrict__ data,
                                                    const float* __restrict__ emb,
                                                    bf16* __restrict__ out) {
  int row = blockIdx.x;            // b*1024 + s
  int s = row & 1023;
  int tok = data[row];
  int d = threadIdx.x * 4;
  floatx4 ev = *(const floatx4*)(emb + (size_t)tok * 1024 + d);
  bf16x4 ov;
#pragma unroll
  for (int pr = 0; pr < 2; pr++) {
    int di = d + pr * 2;
    float e = -(float)di * (13.287712379549449f / 1024.0f);  // log2(10000)/1024
    float freq = exp2f(e);
    float ang = (float)s * freq;
    float sv, cv;
    __sincosf(ang, &sv, &cv);
    ov[pr * 2] = (bf16)(ev[pr * 2] * 32.0f + sv);
    ov[pr * 2 + 1] = (bf16)(ev[pr * 2 + 1] * 32.0f + cv);
  }
  *(bf16x4*)(out + (size_t)row * 1024 + d) = ov;
}

// ---------------- all 7 weight transposes in one dispatch ----------------
// src fp32 [1024][C] -> dst bf16 [C][1024]
struct TransArgs {
  const float* src[7];
  bf16* dst[7];
  int cblk[7];  // C/64
};
__global__ __launch_bounds__(256) void transpose_all_kernel(TransArgs a) {
  int z = blockIdx.z;
  if ((int)blockIdx.x >= a.cblk[z]) return;
  const float* __restrict__ src = a.src[z];
  bf16* __restrict__ dst = a.dst[z];
  int C = a.cblk[z] * 64;
  __shared__ __align__(16) bf16 tile[64][72];
  int c0 = blockIdx.x * 64, r0 = blockIdx.y * 64;
  int t = threadIdx.x;
  int r = t >> 2, cg = (t & 3) * 16;
  const float* sp = src + (size_t)(r0 + r) * C + c0 + cg;
  floatx4 f0 = *(const floatx4*)sp;
  floatx4 f1 = *(const floatx4*)(sp + 4);
  floatx4 f2 = *(const floatx4*)(sp + 8);
  floatx4 f3 = *(const floatx4*)(sp + 12);
  bf16x8 v0, v1;
#pragma unroll
  for (int i = 0; i < 4; i++) {
    v0[i] = (bf16)f0[i];
    v0[4 + i] = (bf16)f1[i];
    v1[i] = (bf16)f2[i];
    v1[4 + i] = (bf16)f3[i];
  }
  *(bf16x8*)&tile[r][cg] = v0;
  *(bf16x8*)&tile[r][cg + 8] = v1;
  __syncthreads();
  bf16x8 o0, o1;
#pragma unroll
  for (int i = 0; i < 8; i++) o0[i] = tile[cg + i][r];
#pragma unroll
  for (int i = 0; i < 8; i++) o1[i] = tile[cg + 8 + i][r];
  bf16* dp = dst + (size_t)(c0 + r) * 1024 + r0 + cg;
  *(bf16x8*)dp = o0;
  *(bf16x8*)(dp + 8) = o1;
}

// ---------------- GEMM: C[m][n] = sum_k A[m][k]*Bt[n][k], K=1024, bf16, m97-style ----------
// LDS tiles [rows][64] unpadded; 16B block b of row r stored at column-block b^(r&7).
// EPI=0: C0[m][n], stride N. EPI=1 (fused QKV, N=3072): n<1024 -> C0 (Q), n<2048 -> C1 (K),
// else -> Vt[((b*16+h)*64+d)][s] transposed store.
template <int EPI, int MT>
__global__ __launch_bounds__(256, 3) void gemm_kernel(const bf16* __restrict__ A,
                                                      const bf16* __restrict__ Bt,
                                                      bf16* __restrict__ C0,
                                                      bf16* __restrict__ C1,
                                                      bf16* __restrict__ Vt, int N) {
  constexpr int NJ = (MT == 128) ? 4 : 2;
  constexpr int PA = MT / 32;   // A-tile async issues per thread
  __shared__ __align__(16) bf16 As[MT * 64];
  __shared__ __align__(16) bf16 Bs[128 * 64];
  const int K = 1024;
  int m0 = blockIdx.x * MT, n0 = blockIdx.y * 128;
  int t = threadIdx.x;
  int l = t & 63, w = t >> 6;
  int lr = l & 15, qd = l >> 4;
  int xorb = lr & 7;
  int wrow = __builtin_amdgcn_readfirstlane(t & 192);  // w*64, wave-uniform
  int wm = (MT == 128) ? (w & 1) : 0;
  int wn = (MT == 128) ? (w >> 1) : w;
  int mwbase = wm * 64;
  int nwbase = (MT == 128) ? (wn * 64) : (wn * 32);
  floatx4 acc[4][NJ] = {};
  for (int k0 = 0; k0 < K; k0 += 64) {
#pragma unroll
    for (int p = 0; p < PA; p++) {
      int jl = p * 256 + t;
      int r = jl >> 3;
      int bi = (jl & 7) ^ (r & 7);
      async_g2l16(A + (size_t)(m0 + r) * K + k0 + bi * 8, &As[(p * 256 + wrow) * 8]);
    }
#pragma unroll
    for (int p = 0; p < 4; p++) {
      int jl = p * 256 + t;
      int r = jl >> 3;
      int bi = (jl & 7) ^ (r & 7);
      async_g2l16(Bt + (size_t)(n0 + r) * K + k0 + bi * 8, &Bs[(p * 256 + wrow) * 8]);
    }
    __syncthreads();
#pragma unroll
    for (int c = 0; c < 2; c++) {
      bf16x8 fa[4], fb[NJ];
#pragma unroll
      for (int i = 0; i < 4; i++)
        fa[i] = *(const bf16x8*)&As[(mwbase + i * 16 + lr) * 64 + ((c * 4 + qd) ^ xorb) * 8];
#pragma unroll
      for (int j = 0; j < NJ; j++)
        fb[j] = *(const bf16x8*)&Bs[(nwbase + j * 16 + lr) * 64 + ((c * 4 + qd) ^ xorb) * 8];
#pragma unroll
      for (int i = 0; i < 4; i++)
#pragma unroll
        for (int j = 0; j < NJ; j++)
          acc[i][j] = __builtin_amdgcn_mfma_f32_16x16x32_bf16(fa[i], fb[j], acc[i][j], 0, 0, 0);
    }
    __syncthreads();
  }
#pragma unroll
  for (int i = 0; i < 4; i++) {
    int mbase = m0 + mwbase + i * 16 + qd * 4;
#pragma unroll
    for (int j = 0; j < NJ; j++) {
      int n = n0 + nwbase + j * 16 + lr;
      if (EPI == 0) {
#pragma unroll
        for (int r = 0; r < 4; r++)
          C0[(size_t)(mbase + r) * N + n] = (bf16)acc[i][j][r];
      } else {
        if (n < 1024) {
#pragma unroll
          for (int r = 0; r < 4; r++)
            C0[(size_t)(mbase + r) * 1024 + n] = (bf16)acc[i][j][r];
        } else if (n < 2048) {
#pragma unroll
          for (int r = 0; r < 4; r++)
            C1[(size_t)(mbase + r) * 1024 + (n - 1024)] = (bf16)acc[i][j][r];
        } else {
          int nn = n - 2048;
          int h = nn >> 6, d = nn & 63;
          int bb = mbase >> 10, s = mbase & 1023;
          bf16x4 v = {(bf16)acc[i][j][0], (bf16)acc[i][j][1],
                      (bf16)acc[i][j][2], (bf16)acc[i][j][3]};
          *(bf16x4*)(Vt + ((size_t)((bb * 16 + h) * 64 + d) << 10) + s) = v;
        }
      }
    }
  }
}

// ---------------- fused flash attention: 256 thr / 4 waves, Br=64 q, Bc=64 keys ----------
// LDS exactly 40 KB (Kt 16K + Vs 16K + P 8K swizzled) -> 4 blocks/CU, no grid tail.
__global__ __launch_bounds__(256, 4) void attn_kernel(const bf16* __restrict__ Q,
                                                      const bf16* __restrict__ Kb,
                                                      const bf16* __restrict__ Vt,
                                                      bf16* __restrict__ O,
                                                      int Skv, int memmode) {
  __shared__ __align__(16) bf16 Kt[2][64 * 64];   // [buf][key][dim], swizzled 16B blocks
  __shared__ __align__(16) bf16 Vs[2][64 * 64];   // [buf][dim][key], swizzled 16B blocks
  __shared__ __align__(16) bf16 Ps[4 * 16 * 64];  // per-wave P tile, swizzled 16B blocks
  int bid = blockIdx.x;                           // 16 qb x 16 h x 4 b = 1024
  int qb = bid & 15, h = (bid >> 4) & 15, b = bid >> 8;
  int t = threadIdx.x, w = t >> 6, l = t & 63;
  int lr = l & 15, qd = l >> 4;
  int xorb = lr & 7;
  int wrow = __builtin_amdgcn_readfirstlane(t & 192);
  int pw = w << 10;                               // w*16*64
  int q0 = qb * 64 + w * 16;
  const bf16* Qrow = Q + (size_t)(b * 1024 + q0 + lr) * 1024 + h * 64;
  bf16x8 aq0 = *(const bf16x8*)(Qrow + qd * 8);
  bf16x8 aq1 = *(const bf16x8*)(Qrow + 32 + qd * 8);
  floatx4 Oacc[4] = {};
  float lsum[4] = {0.f, 0.f, 0.f, 0.f};
  const bf16* Kbase = Kb + (size_t)b * 1024 * 1024 + h * 64;
  const bf16* Vbase = Vt + (size_t)(b * 16 + h) * 64 * 1024;
  int nkt = (Skv + 63) >> 6;

  auto stage = [&](int kt, int bufi) {
    int j0 = kt * 64;
#pragma unroll
    for (int p = 0; p < 2; p++) {
      int jl = p * 256 + t;
      int kr = jl >> 3;                       // key row in tile
      int bi = (jl & 7) ^ (kr & 7);           // swizzled dim-block
      int key = j0 + kr;
      int kc = min(key, Skv - 1);
      int tok = memmode ? (kc < 16 ? 1008 + kc : kc - 16) : kc;
      async_g2l16(Kbase + (size_t)tok * 1024 + bi * 8, &Kt[bufi][(p * 256 + wrow) * 8]);
    }
#pragma unroll
    for (int p = 0; p < 2; p++) {
      int jl = p * 256 + t;
      int dr = jl >> 3;                       // dim row in tile
      int bi = (jl & 7) ^ (dr & 7);           // swizzled key-block
      int jb = j0 + bi * 8;
      int jbc = min(jb, Skv - 8);             // Skv is a multiple of 8
      int tok = memmode ? (jbc < 16 ? 1008 + jbc : jbc - 16) : jbc;
      async_g2l16(Vbase + (size_t)dr * 1024 + tok, &Vs[bufi][(p * 256 + wrow) * 8]);
    }
  };

  stage(0, 0);
  for (int kt = 0; kt < nkt; kt++) {
    int buf = kt & 1;
    __syncthreads();                          // drains tile kt's async loads
    if (kt + 1 < nkt) stage(kt + 1, buf ^ 1); // flies during compute below
    int j0 = kt * 64;
    floatx4 sc[4] = {};
#pragma unroll
    for (int g = 0; g < 4; g++) {
      const bf16* kp = &Kt[buf][(g * 16 + lr) * 64];
      bf16x8 kb0 = *(const bf16x8*)(kp + ((qd ^ xorb) * 8));
      bf16x8 kb1 = *(const bf16x8*)(kp + (((4 + qd) ^ xorb) * 8));
      sc[g] = __builtin_amdgcn_mfma_f32_16x16x32_bf16(aq0, kb0, sc[g], 0, 0, 0);
      sc[g] = __builtin_amdgcn_mfma_f32_16x16x32_bf16(aq1, kb1, sc[g], 0, 0, 0);
    }
#pragma unroll
    for (int g = 0; g < 4; g++) {
      int key = j0 + g * 16 + lr;
      float msk = (key < Skv) ? 1.0f : 0.0f;
      int bcol = (g << 1) | (lr >> 3);
      int c7 = lr & 7;
#pragma unroll
      for (int r = 0; r < 4; r++) {
        int prow = qd * 4 + r;
        float p = exp2f(sc[g][r] * (0.125f * LOG2E)) * msk;
        lsum[r] += p;
        Ps[pw + prow * 64 + (((bcol ^ (prow & 7)) << 3) | c7)] = (bf16)p;
      }
    }
#pragma unroll
    for (int c = 0; c < 2; c++) {
      int cb = c * 4 + qd;
      bf16x8 ap = *(const bf16x8*)&Ps[pw + lr * 64 + ((cb ^ (lr & 7)) << 3)];
#pragma unroll
      for (int tt = 0; tt < 4; tt++) {
        const bf16* vp = &Vs[buf][(tt * 16 + lr) * 64];
        bf16x8 vb = *(const bf16x8*)(vp + ((cb ^ xorb) * 8));
        Oacc[tt] = __builtin_amdgcn_mfma_f32_16x16x32_bf16(ap, vb, Oacc[tt], 0, 0, 0);
      }
    }
  }
#pragma unroll
  for (int r = 0; r < 4; r++) {
    float s = lsum[r];
    s += __shfl_xor(s, 1);
    s += __shfl_xor(s, 2);
    s += __shfl_xor(s, 4);
    s += __shfl_xor(s, 8);
    lsum[r] = 1.0f / s;
  }
#pragma unroll
  for (int tt = 0; tt < 4; tt++)
#pragma unroll
    for (int r = 0; r < 4; r++) {
      size_t orow = (size_t)(b * 1024 + q0 + qd * 4 + r) * 1024 + h * 64 + tt * 16 + lr;
      O[orow] = (bf16)(Oacc[tt][r] * lsum[r]);
    }
}

// ---------------- layernorm: out = LN(x + res) * g + b  (bf16 in, OutT out) ----------------
template <typename OutT>
__global__ __launch_bounds__(256) void ln_kernel(const bf16* __restrict__ x,
                                                 const bf16* __restrict__ res,
                                                 const float* __restrict__ g,
                                                 const float* __restrict__ bta,
                                                 OutT* __restrict__ out) {
  __shared__ float red1[4], red2[4];
  int row = blockIdx.x, t = threadIdx.x;
  size_t base = (size_t)row * 1024 + t * 4;
  bf16x4 xv = *(const bf16x4*)(x + base);
  bf16x4 rv = *(const bf16x4*)(res + base);
  float v[4];
  float s = 0.f;
#pragma unroll
  for (int i = 0; i < 4; i++) {
    v[i] = (float)xv[i] + (float)rv[i];
    s += v[i];
  }
#pragma unroll
  for (int m = 32; m; m >>= 1) s += __shfl_xor(s, m);
  if ((t & 63) == 0) red1[t >> 6] = s;
  __syncthreads();
  float mu = (red1[0] + red1[1] + red1[2] + red1[3]) * (1.0f / 1024.0f);
  float sq = 0.f;
#pragma unroll
  for (int i = 0; i < 4; i++) {
    float dd = v[i] - mu;
    sq += dd * dd;
  }
#pragma unroll
  for (int m = 32; m; m >>= 1) sq += __shfl_xor(sq, m);
  if ((t & 63) == 0) red2[t >> 6] = sq;
  __syncthreads();
  float var = (red2[0] + red2[1] + red2[2] + red2[3]) * (1.0f / 1024.0f);
  float rs = rsqrtf(var + 1e-5f);
  floatx4 gv = *(const floatx4*)(g + t * 4);
  floatx4 bv = *(const floatx4*)(bta + t * 4);
  if constexpr (sizeof(OutT) == 2) {
    bf16x4 ov;
#pragma unroll
    for (int i = 0; i < 4; i++)
      ov[i] = (bf16)((v[i] - mu) * rs * gv[i] + bv[i]);
    *(bf16x4*)(out + base) = ov;
  } else {
    floatx4 ov;
#pragma unroll
    for (int i = 0; i < 4; i++)
      ov[i] = (v[i] - mu) * rs * gv[i] + bv[i];
    *(floatx4*)(out + base) = ov;
  }
}

// ------- fused stage-2 double layernorm + new_mem emit -------
// a = LN(x + hids)*g1 + b1 ; out = LN(hids + a)*g2 + b2 ; rows s>=1008 also emit
// new_mem[b][s-1008][:] = hids row (fp32).
__global__ __launch_bounds__(256) void dualln_kernel(const bf16* __restrict__ x,
                                                     const bf16* __restrict__ hids,
                                                     const float* __restrict__ g1,
                                                     const float* __restrict__ b1,
                                                     const float* __restrict__ g2,
                                                     const float* __restrict__ b2,
                                                     bf16* __restrict__ out,
                                                     float* __restrict__ newmem) {
  __shared__ float ra[4], rb[4], rc[4], rd[4];
  int row = blockIdx.x, t = threadIdx.x;
  size_t base = (size_t)row * 1024 + t * 4;
  bf16x4 xv = *(const bf16x4*)(x + base);
  bf16x4 hv = *(const bf16x4*)(hids + base);
  float hf[4], v[4];
  float s = 0.f;
#pragma unroll
  for (int i = 0; i < 4; i++) {
    hf[i] = (float)hv[i];
    v[i] = (float)xv[i] + hf[i];
    s += v[i];
  }
  int ss = row & 1023;
  if (ss >= 1008) {
    int bb = row >> 10;
    floatx4 mv = {hf[0], hf[1], hf[2], hf[3]};
    *(floatx4*)(newmem + ((size_t)(bb * 16 + ss - 1008) << 10) + t * 4) = mv;
  }
#pragma unroll
  for (int m = 32; m; m >>= 1) s += __shfl_xor(s, m);
  if ((t & 63) == 0) ra[t >> 6] = s;
  __syncthreads();
  float mu = (ra[0] + ra[1] + ra[2] + ra[3]) * (1.0f / 1024.0f);
  float sq = 0.f;
#pragma unroll
  for (int i = 0; i < 4; i++) {
    float dd = v[i] - mu;
    sq += dd * dd;
  }
#pragma unroll
  for (int m = 32; m; m >>= 1) sq += __shfl_xor(sq, m);
  if ((t & 63) == 0) rb[t >> 6] = sq;
  __syncthreads();
  float var = (rb[0] + rb[1] + rb[2] + rb[3]) * (1.0f / 1024.0f);
  float rs = rsqrtf(var + 1e-5f);
  floatx4 g1v = *(const floatx4*)(g1 + t * 4);
  floatx4 b1v = *(const floatx4*)(b1 + t * 4);
  float y[4];
  float s2 = 0.f;
#pragma unroll
  for (int i = 0; i < 4; i++) {
    float a = (v[i] - mu) * rs * g1v[i] + b1v[i];  // attn_out (fp32, not rounded)
    y[i] = hf[i] + a;
    s2 += y[i];
  }
#pragma unroll
  for (int m = 32; m; m >>= 1) s2 += __shfl_xor(s2, m);
  if ((t & 63) == 0) rc[t >> 6] = s2;
  __syncthreads();
  float mu2 = (rc[0] + rc[1] + rc[2] + rc[3]) * (1.0f / 1024.0f);
  float sq2 = 0.f;
#pragma unroll
  for (int i = 0; i < 4; i++) {
    float dd = y[i] - mu2;
    sq2 += dd * dd;
  }
#pragma unroll
  for (int m = 32; m; m >>= 1) sq2 += __shfl_xor(sq2, m);
  if ((t & 63) == 0) rd[t >> 6] = sq2;
  __syncthreads();
  float var2 = (rd[0] + rd[1] + rd[2] + rd[3]) * (1.0f / 1024.0f);
  float rs2 = rsqrtf(var2 + 1e-5f);
  floatx4 g2v = *(const floatx4*)(g2 + t * 4);
  floatx4 b2v = *(const floatx4*)(b2 + t * 4);
  bf16x4 ov;
#pragma unroll
  for (int i = 0; i < 4; i++)
    ov[i] = (bf16)((y[i] - mu2) * rs2 * g2v[i] + b2v[i]);
  *(bf16x4*)(out + base) = ov;
}

extern "C" void kernel_launch(void* const* d_in, const int* in_sizes, int n_in,
                              void* d_out, int out_size, void* d_ws, size_t ws_size,
                              hipStream_t stream) {
  const int* data = (const int*)d_in[0];
  const float* emb = (const float*)d_in[2];
  const float* a_qw = (const float*)d_in[3];
  const float* a_kvw = (const float*)d_in[4];
  const float* a_ow = (const float*)d_in[5];
  const float* a_g = (const float*)d_in[6];
  const float* a_b = (const float*)d_in[7];
  const float* o_qw = (const float*)d_in[16];
  const float* o_kvw = (const float*)d_in[17];
  const float* o_ow = (const float*)d_in[18];
  const float* o_g = (const float*)d_in[19];
  const float* o_b = (const float*)d_in[20];
  const float* ff2_w = (const float*)d_in[21];
  const float* ln1_g = (const float*)d_in[22];
  const float* ln1_b = (const float*)d_in[23];
  const float* ln2_g = (const float*)d_in[24];
  const float* ln2_b = (const float*)d_in[25];
  float* out = (float*)d_out;

  char* ws = (char*)d_ws;
  size_t off = 0;
  auto alloc = [&](size_t elems) {
    bf16* p = (bf16*)(ws + off);
    off += elems * 2;
    return p;
  };
  bf16* Wt_s1 = alloc(3072 * 1024);   // rows 0..1023 = a_qw^T, 1024..3071 = a_kvw^T
  bf16* Wt_s2 = alloc(3072 * 1024);   // rows 0..1023 = o_qw^T, 1024..3071 = o_kvw^T
  bf16* Wt_aow = alloc(1024 * 1024);
  bf16* Wt_oow = alloc(1024 * 1024);
  bf16* Wt_ff2 = alloc(1024 * 1024);
  bf16* hids0 = alloc(4096 * 1024);   // reused for out_attn at the end
  bf16* hids = alloc(4096 * 1024);
  bf16* Qb = alloc(4096 * 1024);      // reused as proj buffer
  bf16* Kb = alloc(4096 * 1024);
  bf16* Vtb = alloc(4096 * 1024);
  bf16* vecb = alloc(4096 * 1024);
  bf16* projb = Qb;

  dim3 tb(256);
  TransArgs ta;
  ta.src[0] = a_qw;  ta.dst[0] = Wt_s1;               ta.cblk[0] = 16;
  ta.src[1] = a_kvw; ta.dst[1] = Wt_s1 + 1024 * 1024; ta.cblk[1] = 32;
  ta.src[2] = o_qw;  ta.dst[2] = Wt_s2;               ta.cblk[2] = 16;
  ta.src[3] = o_kvw; ta.dst[3] = Wt_s2 + 1024 * 1024; ta.cblk[3] = 32;
  ta.src[4] = a_ow;  ta.dst[4] = Wt_aow;              ta.cblk[4] = 16;
  ta.src[5] = o_ow;  ta.dst[5] = Wt_oow;              ta.cblk[5] = 16;
  ta.src[6] = ff2_w; ta.dst[6] = Wt_ff2;              ta.cblk[6] = 16;
  transpose_all_kernel<<<dim3(32, 16, 7), tb, 0, stream>>>(ta);

  embed_kernel<<<4096, tb, 0, stream>>>(data, emb, hids0);

  // stage 1: fused QKV projection + attention + O-proj + LN
  gemm_kernel<1, 128><<<dim3(32, 24), tb, 0, stream>>>(hids0, Wt_s1, Qb, Kb, Vtb, 3072);
  attn_kernel<<<1024, tb, 0, stream>>>(Qb, Kb, Vtb, vecb, 1024, 0);
  gemm_kernel<0, 64><<<dim3(64, 8), tb, 0, stream>>>(vecb, Wt_aow, projb, nullptr, nullptr, 1024);
  ln_kernel<bf16><<<4096, tb, 0, stream>>>(projb, hids0, a_g, a_b, hids);

  // stage 2: attention over [new_mem; hids] (new_mem = hids rows 1008..1023)
  gemm_kernel<1, 128><<<dim3(32, 24), tb, 0, stream>>>(hids, Wt_s2, Qb, Kb, Vtb, 3072);
  attn_kernel<<<1024, tb, 0, stream>>>(Qb, Kb, Vtb, vecb, 1040, 1);
  gemm_kernel<0, 64><<<dim3(64, 8), tb, 0, stream>>>(vecb, Wt_oow, projb, nullptr, nullptr, 1024);
  // fused: o-LN + ln1 + new_mem emit
  dualln_kernel<<<4096, tb, 0, stream>>>(projb, hids, o_g, o_b, ln1_g, ln1_b, hids0,
                                         out + 4194304);

  // final ff + LN -> d_out (fp32)
  gemm_kernel<0, 64><<<dim3(64, 8), tb, 0, stream>>>(hids0, Wt_ff2, projb, nullptr, nullptr, 1024);
  ln_kernel<float><<<4096, tb, 0, stream>>>(projb, hids0, ln2_g, ln2_b, out);
}